// Round 10
// baseline (923.449 us; speedup 1.0000x reference)
//
#include <hip/hip_runtime.h>
#include <hip/hip_cooperative_groups.h>

namespace cg = cooperative_groups;

#define HID 128
#define NTY 8

typedef __attribute__((ext_vector_type(8))) short bf16x8;
typedef __attribute__((ext_vector_type(4))) float f32x4;

__device__ __forceinline__ unsigned short f2bf(float x) {
    unsigned u = __float_as_uint(x);
    u += 0x7FFF + ((u >> 16) & 1);          // RNE
    return (unsigned short)(u >> 16);
}
__device__ __forceinline__ float bf2f(unsigned short s) {
    return __uint_as_float(((unsigned)s) << 16);
}
__device__ __forceinline__ float sigmoidf_fast(float x) {
    return 1.f / (1.f + __expf(-x));
}
__device__ __forceinline__ float tanhf_fast(float x) {
    return 1.f - 2.f / (1.f + __expf(2.f * x));
}

// ---------------- ONE cooperative kernel: conv/init + (type,dst) counting sort ----------------
// P0 conv: h->bf16, W->wfr frags, GRU->wpkf frags, sortedE=-1, seg8=0  (R9-proven formulas)
// P1 hist -> P2 block-local scan (scanA pattern) -> P3 bsum scan + pads -> P4 finalize -> P5 scatter
// After: seg8[k] = padded END of segment k (ends-after-scatter contract, as R9); padB = type bases.
__global__ __launch_bounds__(256) void prep_sort_coop(
    const float* __restrict__ h, unsigned short* __restrict__ hbf, int nh,
    const float* __restrict__ W, unsigned short* __restrict__ wfr,
    const float* __restrict__ wih, const float* __restrict__ whh,
    unsigned short* __restrict__ wpkf,
    const int* __restrict__ ei, const int* __restrict__ etype, int E, int N,
    int* __restrict__ seg8, int* __restrict__ bsum,
    int* __restrict__ padB, int* __restrict__ padA,
    int* __restrict__ sortedE, int capE)
{
    cg::grid_group grid = cg::this_grid();
    __shared__ int s[256];

    int tx = threadIdx.x;
    int gtid = blockIdx.x * 256 + tx;
    int gsz = gridDim.x * 256;
    int nb = gridDim.x;
    int M8 = N * 8;
    int CB = (M8 + nb - 1) / nb;            // per-block scan chunk

    // ---- P0: conv + init (grid-stride; R9-proven index math) ----
    for (int i = gtid; i < nh; i += gsz) hbf[i] = f2bf(h[i]);
    for (int i = gtid; i < 131072; i += gsz) {
        int e = i & 7, lane = (i >> 3) & 63, cb = (i >> 9) & 7, kc = (i >> 12) & 3, t = i >> 14;
        int lr = lane & 15, quad = lane >> 4;
        int d = cb * 16 + lr;
        int k = kc * 32 + quad * 8 + e;
        wfr[i] = f2bf(W[(t << 14) + (k << 7) + d]);
    }
    for (int i = gtid; i < 98304; i += gsz) {
        int e = i & 7, lane = (i >> 3) & 63, f = i >> 9;   // f = kc*24+g3*8+ct
        int ct = f & 7, fg = f >> 3;                       // fg = kc*3+g3
        int g3 = fg % 3, kc = fg / 3;
        int lr = lane & 15, quad = lane >> 4;
        int d = ct * 16 + lr;
        int kk = quad * 8 + e;
        float v;
        if (kc < 4) v = wih[(g3 * 128 + d) * 128 + kc * 32 + kk];
        else        v = whh[(g3 * 128 + d) * 128 + (kc - 4) * 32 + kk];
        wpkf[i] = f2bf(v);
    }
    for (int i = gtid; i < capE; i += gsz) sortedE[i] = -1;
    for (int i = gtid; i < M8; i += gsz) seg8[i] = 0;
    grid.sync();

    // ---- P1: histogram over key = type*N + dst ----
    for (int i = gtid; i < E; i += gsz)
        atomicAdd(&seg8[etype[i] * N + ei[E + i]], 1);
    grid.sync();

    // ---- P2: block-local exclusive scan of chunk [b*CB, b*CB+CB) ----
    {
        int b0 = blockIdx.x * CB;
        int bend = b0 + CB; if (bend > M8) bend = M8;
        int cpt = (CB + 255) / 256;
        int t0 = b0 + tx * cpt;
        int t1 = t0 + cpt; if (t1 > bend) t1 = bend;
        int sum = 0;
        for (int k = t0; k < t1; ++k) sum += seg8[k];
        s[tx] = sum;
        __syncthreads();
        for (int off = 1; off < 256; off <<= 1) {
            int t = (tx >= off) ? s[tx - off] : 0;
            __syncthreads();
            s[tx] += t;
            __syncthreads();
        }
        int run = s[tx] - sum;
        for (int k = t0; k < t1; ++k) { int v = seg8[k]; seg8[k] = run; run += v; }
        if (tx == 255) bsum[blockIdx.x] = s[255];
    }
    grid.sync();

    // ---- P3: block 0 scans bsum + computes per-type padded bases ----
    if (blockIdx.x == 0) {
        int cpt = (nb + 255) / 256;
        int t0 = tx * cpt;
        int t1 = t0 + cpt; if (t1 > nb) t1 = nb;
        int sum = 0;
        for (int k = t0; k < t1; ++k) sum += bsum[k];
        s[tx] = sum;
        __syncthreads();
        for (int off = 1; off < 256; off <<= 1) {
            int t = (tx >= off) ? s[tx - off] : 0;
            __syncthreads();
            s[tx] += t;
            __syncthreads();
        }
        int run = s[tx] - sum;
        for (int k = t0; k < t1; ++k) { int v = bsum[k]; bsum[k] = run; run += v; }
        __syncthreads();
        if (tx == 0) {
            int r[9];
            for (int t = 0; t < 8; ++t) {
                int k = t * N;
                r[t] = seg8[k] + bsum[k / CB];
            }
            r[8] = E;
            int pb = 0;
            for (int t = 0; t < 8; ++t) {
                padB[t] = pb;
                padA[t] = pb - r[t];
                int c = r[t + 1] - r[t];
                pb += (c + 127) & ~127;
            }
            padB[8] = pb;
        }
    }
    grid.sync();

    // ---- P4: finalize seg8[i] = padded global start of segment i ----
    for (int i = gtid; i < M8; i += gsz)
        seg8[i] += bsum[i / CB] + padA[i / N];
    grid.sync();

    // ---- P5: scatter (consumes seg8 cursor -> segment ENDS) ----
    for (int i = gtid; i < E; i += gsz) {
        int pos = atomicAdd(&seg8[etype[i] * N + ei[E + i]], 1);
        sortedE[pos] = ei[i];   // src node id
    }
}

// ---------------- msg GEMM: 128-edge x 128-d tile (R9 verbatim) ----------------
__global__ __launch_bounds__(256) void msg_gemm(
    const unsigned short* __restrict__ hbf, const unsigned short* __restrict__ wfr,
    const float* __restrict__ bias, const int* __restrict__ sortedE,
    const int* __restrict__ padB, unsigned short* __restrict__ M)
{
    __shared__ unsigned short hs[128][136];
    __shared__ int srcs[128];
    __shared__ int stype;

    int tx = threadIdx.x;
    int base = blockIdx.x * 128;
    if (tx < 128) srcs[tx] = sortedE[base + tx];
    if (tx == 0) {
        int t = -1;
        #pragma unroll
        for (int tt = 0; tt < 8; ++tt)
            if (base >= padB[tt] && base < padB[tt + 1]) t = tt;
        stype = t;
    }
    __syncthreads();
    int t = stype;
    if (t < 0) return;

    for (int f = tx; f < 2048; f += 256) {
        int row = f >> 4, c8 = (f & 15) * 8;
        int s = srcs[row]; if (s < 0) s = 0;
        *(uint4*)&hs[row][c8] = *(const uint4*)&hbf[(size_t)s * 128 + c8];
    }
    __syncthreads();

    int lane = tx & 63, w = tx >> 6;
    int r0 = (w >> 1) * 64, c0 = (w & 1) * 64;
    int lr = lane & 15, quad = lane >> 4;
    f32x4 acc[4][4] = {};

    const unsigned short* wt = wfr + (t << 14) + ((unsigned)(c0 >> 4) << 9) + (lane << 3);
    #pragma unroll
    for (int kc = 0; kc < 4; ++kc) {
        bf16x8 af[4], wf[4];
        #pragma unroll
        for (int rb = 0; rb < 4; ++rb) af[rb] = *(const bf16x8*)&hs[r0 + rb * 16 + lr][kc * 32 + quad * 8];
        #pragma unroll
        for (int cb = 0; cb < 4; ++cb) wf[cb] = *(const bf16x8*)&wt[(kc << 12) + (cb << 9)];
        #pragma unroll
        for (int rb = 0; rb < 4; ++rb)
            #pragma unroll
            for (int cb = 0; cb < 4; ++cb)
                acc[rb][cb] = __builtin_amdgcn_mfma_f32_16x16x32_bf16(wf[cb], af[rb], acc[rb][cb], 0, 0, 0);
    }

    float4 bv4[4];
    #pragma unroll
    for (int cb = 0; cb < 4; ++cb)
        bv4[cb] = *(const float4*)&bias[t * 128 + c0 + cb * 16 + quad * 4];

    #pragma unroll
    for (int rb = 0; rb < 4; ++rb) {
        int e = r0 + rb * 16 + lr;
        size_t mrow = (size_t)(base + e);
        #pragma unroll
        for (int cb = 0; cb < 4; ++cb) {
            int d0 = c0 + cb * 16 + quad * 4;
            f32x4 a = acc[rb][cb];
            uint2 v;
            v.x = (unsigned)f2bf(a[0] + bv4[cb].x) | ((unsigned)f2bf(a[1] + bv4[cb].y) << 16);
            v.y = (unsigned)f2bf(a[2] + bv4[cb].z) | ((unsigned)f2bf(a[3] + bv4[cb].w) << 16);
            *(uint2*)&M[mrow * 128 + d0] = v;
        }
    }
}

// ---------------- fused seg-reduce + GRU (R9 verbatim) ----------------
__global__ __launch_bounds__(512, 4) void gru_fused(
    const unsigned short* __restrict__ M, const int* __restrict__ segE,
    const int* __restrict__ padB, const unsigned short* __restrict__ hbf,
    const unsigned short* __restrict__ wpkf, const float* __restrict__ bih,
    const float* __restrict__ bhh, const float* __restrict__ hf,
    float* __restrict__ out, int N)
{
    __shared__ unsigned short As[4][2048];
    __shared__ int bnds_l[520];

    int tx = threadIdx.x;
    int n0 = blockIdx.x * 64;

    for (int jl = tx; jl < 520; jl += 512) {
        int t = jl / 65, j = jl - t * 65;
        int nidx = n0 + j - 1;
        int v;
        if (nidx < 0) v = padB[t];
        else {
            if (nidx > N - 1) nidx = N - 1;
            v = segE[t * N + nidx];
        }
        bnds_l[jl] = v;
    }

    int lane = tx & 63, w = tx >> 6;
    int lr = lane & 15, quad = lane >> 4;
    int rt = w & 3, cg = w >> 2;
    int node = n0 + rt * 16 + lr;
    bool valid = node < N;
    int nc = valid ? node : (N - 1);

    bf16x8 afh[4];
    {
        const unsigned short* hrow = hbf + ((size_t)nc << 7) + (quad << 3);
        #pragma unroll
        for (int k4 = 0; k4 < 4; ++k4) afh[k4] = *(const bf16x8*)&hrow[k4 * 32];
    }
    __syncthreads();

    {
        int ln = tx >> 3, j8 = tx & 7;
        float a[16];
        #pragma unroll
        for (int j = 0; j < 16; ++j) a[j] = 0.f;

        int tcur = 0;
        int r = bnds_l[ln], re = bnds_l[ln + 1];
        while (r >= re && tcur < 7) {
            ++tcur;
            r = bnds_l[tcur * 65 + ln];
            re = bnds_l[tcur * 65 + ln + 1];
        }
        bool have = (r < re);
        uint4 c0v, c1v;
        if (have) {
            const unsigned short* p = M + (size_t)r * 128 + j8 * 16;
            c0v = *(const uint4*)p;
            c1v = *(const uint4*)(p + 8);
        }
        while (have) {
            uint4 p0 = c0v, p1 = c1v;
            int rn = r + 1, tn = tcur, ren = re;
            while (rn >= ren && tn < 7) {
                ++tn;
                rn = bnds_l[tn * 65 + ln];
                ren = bnds_l[tn * 65 + ln + 1];
            }
            bool haveN = (rn < ren);
            if (haveN) {
                const unsigned short* p = M + (size_t)rn * 128 + j8 * 16;
                c0v = *(const uint4*)p;
                c1v = *(const uint4*)(p + 8);
            }
            const unsigned short* q0 = (const unsigned short*)&p0;
            const unsigned short* q1 = (const unsigned short*)&p1;
            #pragma unroll
            for (int u = 0; u < 8; ++u) {
                a[u]     += bf2f(q0[u]);
                a[8 + u] += bf2f(q1[u]);
            }
            r = rn; tcur = tn; re = ren; have = haveN;
        }

        unsigned short tmp[16];
        #pragma unroll
        for (int j = 0; j < 16; ++j) tmp[j] = f2bf(a[j]);
        int lrw = ln & 15, wv = ln >> 4;
        int swz = (lrw & 7) << 4;
        int b0 = ((lrw << 8) + (j8 << 5)) ^ swz;
        int b1 = ((lrw << 8) + (j8 << 5) + 16) ^ swz;
        *(uint4*)((char*)&As[wv][0] + b0) = *(const uint4*)&tmp[0];
        *(uint4*)((char*)&As[wv][0] + b1) = *(const uint4*)&tmp[8];
    }
    __syncthreads();

    const unsigned short* AsW = &As[rt][0];
    const unsigned short* wg = wpkf + (lane << 3);

    f32x4 aR[4] = {}, aZ[4] = {}, aI[4] = {}, aH[4] = {};
    #pragma unroll
    for (int kc = 0; kc < 8; ++kc) {
        bf16x8 af;
        if (kc < 4) {
            int byte = ((lr << 8) + (kc << 6) + (quad << 4)) ^ ((lr & 7) << 4);
            af = *(const bf16x8*)((char*)AsW + byte);
        } else {
            af = afh[kc - 4];
        }
        #pragma unroll
        for (int g3 = 0; g3 < 3; ++g3) {
            #pragma unroll
            for (int ct = 0; ct < 4; ++ct) {
                bf16x8 wf = *(const bf16x8*)&wg[(unsigned)((kc * 3 + g3) * 8 + cg * 4 + ct) << 9];
                if (g3 == 0)      aR[ct] = __builtin_amdgcn_mfma_f32_16x16x32_bf16(wf, af, aR[ct], 0, 0, 0);
                else if (g3 == 1) aZ[ct] = __builtin_amdgcn_mfma_f32_16x16x32_bf16(wf, af, aZ[ct], 0, 0, 0);
                else if (kc < 4)  aI[ct] = __builtin_amdgcn_mfma_f32_16x16x32_bf16(wf, af, aI[ct], 0, 0, 0);
                else              aH[ct] = __builtin_amdgcn_mfma_f32_16x16x32_bf16(wf, af, aH[ct], 0, 0, 0);
            }
        }
    }

    if (valid) {
        #pragma unroll
        for (int ct = 0; ct < 4; ++ct) {
            int d0 = cg * 64 + ct * 16 + quad * 4;
            f32x4 bir = *(const f32x4*)&bih[d0],       bhr = *(const f32x4*)&bhh[d0];
            f32x4 biz = *(const f32x4*)&bih[128 + d0], bhz = *(const f32x4*)&bhh[128 + d0];
            f32x4 bin = *(const f32x4*)&bih[256 + d0], bhn = *(const f32x4*)&bhh[256 + d0];
            f32x4 h0 = *(const f32x4*)&hf[(size_t)node * 128 + d0];
            f32x4 o;
            #pragma unroll
            for (int j = 0; j < 4; ++j) {
                float r  = sigmoidf_fast(aR[ct][j] + bir[j] + bhr[j]);
                float z  = sigmoidf_fast(aZ[ct][j] + biz[j] + bhz[j]);
                float nn = tanhf_fast(aI[ct][j] + bin[j] + r * (aH[ct][j] + bhn[j]));
                o[j] = (1.f - z) * nn + z * h0[j];
            }
            *(f32x4*)&out[(size_t)node * 128 + d0] = o;
        }
    }
}

extern "C" void kernel_launch(void* const* d_in, const int* in_sizes, int n_in,
                              void* d_out, int out_size, void* d_ws, size_t ws_size,
                              hipStream_t stream)
{
    const float* h     = (const float*)d_in[0];
    const int*   ei    = (const int*)d_in[1];
    const int*   etype = (const int*)d_in[2];
    const float* W     = (const float*)d_in[3];
    const float* b     = (const float*)d_in[4];
    const float* wih   = (const float*)d_in[5];
    const float* whh   = (const float*)d_in[6];
    const float* bih   = (const float*)d_in[7];
    const float* bhh   = (const float*)d_in[8];
    float* out = (float*)d_out;

    int E = in_sizes[1] / 2;
    int N = in_sizes[0] / HID;
    int M8 = N * 8;
    int capE = ((E + 127) / 128 + NTY) * 128;   // upper bound on padded total
    int nh = N * 128;

    char* p = (char*)d_ws;
    auto alloc = [&](size_t bytes) { char* r = p; p += (bytes + 255) & ~(size_t)255; return r; };
    unsigned short* hbf  = (unsigned short*)alloc((size_t)nh * 2);
    unsigned short* wfr  = (unsigned short*)alloc((size_t)131072 * 2);
    unsigned short* wpkf = (unsigned short*)alloc((size_t)98304 * 2);
    int* seg8    = (int*)alloc((size_t)M8 * 4);
    int* bsum    = (int*)alloc(1024 * 4);
    int* sortedE = (int*)alloc((size_t)capE * 4);
    int* padB    = (int*)alloc(9 * 4);
    int* padA    = (int*)alloc(8 * 4);
    unsigned short* M = (unsigned short*)alloc((size_t)capE * 128 * 2);
    (void)ws_size;

    void* args[] = {
        (void*)&h, (void*)&hbf, (void*)&nh,
        (void*)&W, (void*)&wfr,
        (void*)&wih, (void*)&whh, (void*)&wpkf,
        (void*)&ei, (void*)&etype, (void*)&E, (void*)&N,
        (void*)&seg8, (void*)&bsum, (void*)&padB, (void*)&padA,
        (void*)&sortedE, (void*)&capE
    };
    hipLaunchCooperativeKernel((const void*)prep_sort_coop,
                               dim3(1024), dim3(256), args, 0, stream);

    msg_gemm<<<capE / 128, 256, 0, stream>>>(hbf, wfr, b, sortedE, padB, M);
    gru_fused<<<(N + 63) / 64, 512, 0, stream>>>(M, seg8, padB, hbf, wpkf, bih, bhh, h, out, N);
}

// Round 12
// 357.815 us; speedup vs baseline: 2.5808x; 2.5808x over previous
//
#include <hip/hip_runtime.h>

#define HID 128
#define NTY 8

typedef __attribute__((ext_vector_type(8))) short bf16x8;
typedef __attribute__((ext_vector_type(4))) float f32x4;

__device__ __forceinline__ unsigned short f2bf(float x) {
    unsigned u = __float_as_uint(x);
    u += 0x7FFF + ((u >> 16) & 1);          // RNE
    return (unsigned short)(u >> 16);
}
__device__ __forceinline__ float bf2f(unsigned short s) {
    return __uint_as_float(((unsigned)s) << 16);
}
__device__ __forceinline__ float sigmoidf_fast(float x) {
    return 1.f / (1.f + __expf(-x));
}
__device__ __forceinline__ float tanhf_fast(float x) {
    return 1.f - 2.f / (1.f + __expf(2.f * x));
}

// ---------------- conv + histogram in ONE kernel ----------------
// conv formulas R9-proven. seg8 pre-zeroed by hipMemsetAsync; hist atomics are
// independent of conv outputs, so they overlap the streaming conversions.
__global__ __launch_bounds__(256) void conv_hist(
    const float* __restrict__ h, unsigned short* __restrict__ hbf, int nh,
    const float* __restrict__ W, unsigned short* __restrict__ wfr,
    const float* __restrict__ wih, const float* __restrict__ whh,
    unsigned short* __restrict__ wpkf,
    const int* __restrict__ ei, const int* __restrict__ etype, int E, int N,
    int* __restrict__ seg8)
{
    int gtid = blockIdx.x * 256 + threadIdx.x;
    int gsz = gridDim.x * 256;

    for (int i = gtid; i < nh; i += gsz) hbf[i] = f2bf(h[i]);
    for (int i = gtid; i < 131072; i += gsz) {
        int e = i & 7, lane = (i >> 3) & 63, cb = (i >> 9) & 7, kc = (i >> 12) & 3, t = i >> 14;
        int lr = lane & 15, quad = lane >> 4;
        int d = cb * 16 + lr;
        int k = kc * 32 + quad * 8 + e;
        wfr[i] = f2bf(W[(t << 14) + (k << 7) + d]);
    }
    for (int i = gtid; i < 98304; i += gsz) {
        int e = i & 7, lane = (i >> 3) & 63, f = i >> 9;   // f = kc*24+g3*8+ct
        int ct = f & 7, fg = f >> 3;                       // fg = kc*3+g3
        int g3 = fg % 3, kc = fg / 3;
        int lr = lane & 15, quad = lane >> 4;
        int d = ct * 16 + lr;
        int kk = quad * 8 + e;
        float v;
        if (kc < 4) v = wih[(g3 * 128 + d) * 128 + kc * 32 + kk];
        else        v = whh[(g3 * 128 + d) * 128 + (kc - 4) * 32 + kk];
        wpkf[i] = f2bf(v);
    }
    // histogram over key = type*N + dst
    for (int i = gtid; i < E; i += gsz)
        atomicAdd(&seg8[etype[i] * N + ei[E + i]], 1);
}

// block-local exclusive scan (256/block) + per-block sums (R9 verbatim)
__global__ void scanA_kernel(int* __restrict__ seg8, int* __restrict__ bsum, int M8) {
    __shared__ int s[256];
    int i = blockIdx.x * 256 + threadIdx.x;
    int v = (i < M8) ? seg8[i] : 0;
    s[threadIdx.x] = v;
    __syncthreads();
    for (int off = 1; off < 256; off <<= 1) {
        int t = (threadIdx.x >= off) ? s[threadIdx.x - off] : 0;
        __syncthreads();
        s[threadIdx.x] += t;
        __syncthreads();
    }
    if (i < M8) seg8[i] = s[threadIdx.x] - v;
    if (threadIdx.x == 255) bsum[blockIdx.x] = s[255];
}

// block-sum scan + per-type padded bases + true (unpadded) region ends
__global__ void scanBbig_kernel(int* __restrict__ bsum, int nb,
                                const int* __restrict__ seg8, int N, int E,
                                int* __restrict__ padB, int* __restrict__ padA,
                                int* __restrict__ trueE) {
    __shared__ int s[256];
    int tx = threadIdx.x;
    int C = (nb + 255) / 256;
    int lo = tx * C, hi = lo + C; if (hi > nb) hi = nb;
    int sum = 0;
    for (int j = lo; j < hi; ++j) sum += bsum[j];
    s[tx] = sum;
    __syncthreads();
    for (int off = 1; off < 256; off <<= 1) {
        int t = (tx >= off) ? s[tx - off] : 0;
        __syncthreads();
        s[tx] += t;
        __syncthreads();
    }
    int run = s[tx] - sum;
    for (int j = lo; j < hi; ++j) { int v = bsum[j]; bsum[j] = run; run += v; }
    __syncthreads();
    if (tx == 0) {
        int r[9];
        for (int t = 0; t < 8; ++t) { int k = t * N; r[t] = seg8[k] + bsum[k >> 8]; }
        r[8] = E;
        int pb = 0;
        for (int t = 0; t < 8; ++t) {
            padB[t] = pb;
            padA[t] = pb - r[t];
            int c = r[t + 1] - r[t];
            trueE[t] = pb + c;
            pb += (c + 127) & ~127;
        }
        padB[8] = pb;
    }
}

// scatter with LOCAL cursor + on-the-fly globalization (scanC eliminated).
// After: seg8[k] = LOCAL end of segment k; global end = seg8[k] + bsum[k>>8] + padA[t].
__global__ void scatter8_kernel(const int* __restrict__ etype, const int* __restrict__ ei,
                                int E, int N, int* __restrict__ seg8,
                                const int* __restrict__ bsum, const int* __restrict__ padA,
                                int* __restrict__ sortedE) {
    int stride = gridDim.x * blockDim.x;
    for (int i = blockIdx.x * blockDim.x + threadIdx.x; i < E; i += stride) {
        int t = etype[i];
        int k = t * N + ei[E + i];
        int lp = atomicAdd(&seg8[k], 1);
        sortedE[lp + bsum[k >> 8] + padA[t]] = ei[i];   // src node id
    }
}

// ---------------- msg GEMM: 128-edge x 128-d tile (R9 + trueE clamp, no sortedE init) ----------------
__global__ __launch_bounds__(256) void msg_gemm(
    const unsigned short* __restrict__ hbf, const unsigned short* __restrict__ wfr,
    const float* __restrict__ bias, const int* __restrict__ sortedE,
    const int* __restrict__ padB, const int* __restrict__ trueE,
    unsigned short* __restrict__ M)
{
    __shared__ unsigned short hs[128][136];
    __shared__ int srcs[128];
    __shared__ int stype, send;

    int tx = threadIdx.x;
    int base = blockIdx.x * 128;
    if (tx == 0) {
        int t = -1;
        #pragma unroll
        for (int tt = 0; tt < 8; ++tt)
            if (base >= padB[tt] && base < padB[tt + 1]) t = tt;
        stype = t;
        send = (t >= 0) ? trueE[t] : 0;
    }
    __syncthreads();
    int t = stype;
    if (t < 0) return;
    int sEnd = send;
    if (tx < 128) srcs[tx] = (base + tx < sEnd) ? sortedE[base + tx] : 0;
    __syncthreads();

    for (int f = tx; f < 2048; f += 256) {
        int row = f >> 4, c8 = (f & 15) * 8;
        int s = srcs[row];
        *(uint4*)&hs[row][c8] = *(const uint4*)&hbf[(size_t)s * 128 + c8];
    }
    __syncthreads();

    int lane = tx & 63, w = tx >> 6;
    int r0 = (w >> 1) * 64, c0 = (w & 1) * 64;
    int lr = lane & 15, quad = lane >> 4;
    f32x4 acc[4][4] = {};

    const unsigned short* wt = wfr + (t << 14) + ((unsigned)(c0 >> 4) << 9) + (lane << 3);
    #pragma unroll
    for (int kc = 0; kc < 4; ++kc) {
        bf16x8 af[4], wf[4];
        #pragma unroll
        for (int rb = 0; rb < 4; ++rb) af[rb] = *(const bf16x8*)&hs[r0 + rb * 16 + lr][kc * 32 + quad * 8];
        #pragma unroll
        for (int cb = 0; cb < 4; ++cb) wf[cb] = *(const bf16x8*)&wt[(kc << 12) + (cb << 9)];
        #pragma unroll
        for (int rb = 0; rb < 4; ++rb)
            #pragma unroll
            for (int cb = 0; cb < 4; ++cb)
                acc[rb][cb] = __builtin_amdgcn_mfma_f32_16x16x32_bf16(wf[cb], af[rb], acc[rb][cb], 0, 0, 0);
    }

    float4 bv4[4];
    #pragma unroll
    for (int cb = 0; cb < 4; ++cb)
        bv4[cb] = *(const float4*)&bias[t * 128 + c0 + cb * 16 + quad * 4];

    #pragma unroll
    for (int rb = 0; rb < 4; ++rb) {
        int e = r0 + rb * 16 + lr;
        size_t mrow = (size_t)(base + e);
        #pragma unroll
        for (int cb = 0; cb < 4; ++cb) {
            int d0 = c0 + cb * 16 + quad * 4;
            f32x4 a = acc[rb][cb];
            uint2 v;
            v.x = (unsigned)f2bf(a[0] + bv4[cb].x) | ((unsigned)f2bf(a[1] + bv4[cb].y) << 16);
            v.y = (unsigned)f2bf(a[2] + bv4[cb].z) | ((unsigned)f2bf(a[3] + bv4[cb].w) << 16);
            *(uint2*)&M[mrow * 128 + d0] = v;
        }
    }
}

// ---------------- fused seg-reduce + GRU: stage A = 4 interleaved chains (2 type-runs each) ----------------
__global__ __launch_bounds__(512, 4) void gru_fused(
    const unsigned short* __restrict__ M, const int* __restrict__ segE,
    const int* __restrict__ bsum, const int* __restrict__ padA,
    const int* __restrict__ padB, const unsigned short* __restrict__ hbf,
    const unsigned short* __restrict__ wpkf, const float* __restrict__ bih,
    const float* __restrict__ bhh, const float* __restrict__ hf,
    float* __restrict__ out, int N)
{
    __shared__ unsigned short As[4][2048];
    __shared__ int bnds_l[520];

    int tx = threadIdx.x;
    int n0 = blockIdx.x * 64;

    // bounds, globalized on the fly: end(t,nidx) = segE[k] + bsum[k>>8] + padA[t]
    for (int jl = tx; jl < 520; jl += 512) {
        int t = jl / 65, j = jl - t * 65;
        int nidx = n0 + j - 1;
        int v;
        if (nidx < 0) v = padB[t];
        else {
            if (nidx > N - 1) nidx = N - 1;
            int k = t * N + nidx;
            v = segE[k] + bsum[k >> 8] + padA[t];
        }
        bnds_l[jl] = v;
    }

    int lane = tx & 63, w = tx >> 6;
    int lr = lane & 15, quad = lane >> 4;
    int rt = w & 3, cg = w >> 2;
    int node = n0 + rt * 16 + lr;
    bool valid = node < N;
    int nc = valid ? node : (N - 1);

    bf16x8 afh[4];
    {
        const unsigned short* hrow = hbf + ((size_t)nc << 7) + (quad << 3);
        #pragma unroll
        for (int k4 = 0; k4 < 4; ++k4) afh[k4] = *(const bf16x8*)&hrow[k4 * 32];
    }
    __syncthreads();   // bnds ready

    // ---- stage A: 4 chains x 2 type-runs, interleaved -> 4 outstanding loads/thread ----
    {
        int ln = tx >> 3, j8 = tx & 7;
        float a[16];
        #pragma unroll
        for (int j = 0; j < 16; ++j) a[j] = 0.f;

        int rr[4], ree[4], tc[4];
        bool hv[4];
        uint4 pb0[4], pb1[4];
        #pragma unroll
        for (int c = 0; c < 4; ++c) {
            int t0 = 2 * c;
            int r = bnds_l[t0 * 65 + ln], re = bnds_l[t0 * 65 + ln + 1];
            int tcc = t0;
            if (r >= re) {
                tcc = t0 + 1;
                r = bnds_l[tcc * 65 + ln];
                re = bnds_l[tcc * 65 + ln + 1];
            }
            hv[c] = (r < re);
            rr[c] = r; ree[c] = re; tc[c] = tcc;
            if (hv[c]) {
                const unsigned short* p = M + (size_t)r * 128 + j8 * 16;
                pb0[c] = *(const uint4*)p;
                pb1[c] = *(const uint4*)(p + 8);
            }
        }
        while (hv[0] | hv[1] | hv[2] | hv[3]) {
            #pragma unroll
            for (int c = 0; c < 4; ++c) {
                if (hv[c]) {
                    uint4 p0 = pb0[c], p1 = pb1[c];
                    int rn = rr[c] + 1, tn = tc[c], ren = ree[c];
                    if (rn >= ren && tn == 2 * c) {
                        tn = 2 * c + 1;
                        rn = bnds_l[tn * 65 + ln];
                        ren = bnds_l[tn * 65 + ln + 1];
                    }
                    bool hN = (rn < ren);
                    if (hN) {
                        const unsigned short* p = M + (size_t)rn * 128 + j8 * 16;
                        pb0[c] = *(const uint4*)p;
                        pb1[c] = *(const uint4*)(p + 8);
                    }
                    const unsigned short* q0 = (const unsigned short*)&p0;
                    const unsigned short* q1 = (const unsigned short*)&p1;
                    #pragma unroll
                    for (int u = 0; u < 8; ++u) {
                        a[u]     += bf2f(q0[u]);
                        a[8 + u] += bf2f(q1[u]);
                    }
                    rr[c] = rn; tc[c] = tn; ree[c] = ren; hv[c] = hN;
                }
            }
        }

        unsigned short tmp[16];
        #pragma unroll
        for (int j = 0; j < 16; ++j) tmp[j] = f2bf(a[j]);
        int lrw = ln & 15, wv = ln >> 4;
        int swz = (lrw & 7) << 4;
        int b0 = ((lrw << 8) + (j8 << 5)) ^ swz;
        int b1 = ((lrw << 8) + (j8 << 5) + 16) ^ swz;
        *(uint4*)((char*)&As[wv][0] + b0) = *(const uint4*)&tmp[0];
        *(uint4*)((char*)&As[wv][0] + b1) = *(const uint4*)&tmp[8];
    }
    __syncthreads();

    // ---- GRU: single-pass parallel gates (R9 verbatim) ----
    const unsigned short* AsW = &As[rt][0];
    const unsigned short* wg = wpkf + (lane << 3);

    f32x4 aR[4] = {}, aZ[4] = {}, aI[4] = {}, aH[4] = {};
    #pragma unroll
    for (int kc = 0; kc < 8; ++kc) {
        bf16x8 af;
        if (kc < 4) {
            int byte = ((lr << 8) + (kc << 6) + (quad << 4)) ^ ((lr & 7) << 4);
            af = *(const bf16x8*)((char*)AsW + byte);
        } else {
            af = afh[kc - 4];
        }
        #pragma unroll
        for (int g3 = 0; g3 < 3; ++g3) {
            #pragma unroll
            for (int ct = 0; ct < 4; ++ct) {
                bf16x8 wf = *(const bf16x8*)&wg[(unsigned)((kc * 3 + g3) * 8 + cg * 4 + ct) << 9];
                if (g3 == 0)      aR[ct] = __builtin_amdgcn_mfma_f32_16x16x32_bf16(wf, af, aR[ct], 0, 0, 0);
                else if (g3 == 1) aZ[ct] = __builtin_amdgcn_mfma_f32_16x16x32_bf16(wf, af, aZ[ct], 0, 0, 0);
                else if (kc < 4)  aI[ct] = __builtin_amdgcn_mfma_f32_16x16x32_bf16(wf, af, aI[ct], 0, 0, 0);
                else              aH[ct] = __builtin_amdgcn_mfma_f32_16x16x32_bf16(wf, af, aH[ct], 0, 0, 0);
            }
        }
    }

    if (valid) {
        #pragma unroll
        for (int ct = 0; ct < 4; ++ct) {
            int d0 = cg * 64 + ct * 16 + quad * 4;
            f32x4 bir = *(const f32x4*)&bih[d0],       bhr = *(const f32x4*)&bhh[d0];
            f32x4 biz = *(const f32x4*)&bih[128 + d0], bhz = *(const f32x4*)&bhh[128 + d0];
            f32x4 bin = *(const f32x4*)&bih[256 + d0], bhn = *(const f32x4*)&bhh[256 + d0];
            f32x4 h0 = *(const f32x4*)&hf[(size_t)node * 128 + d0];
            f32x4 o;
            #pragma unroll
            for (int j = 0; j < 4; ++j) {
                float r  = sigmoidf_fast(aR[ct][j] + bir[j] + bhr[j]);
                float z  = sigmoidf_fast(aZ[ct][j] + biz[j] + bhz[j]);
                float nn = tanhf_fast(aI[ct][j] + bin[j] + r * (aH[ct][j] + bhn[j]));
                o[j] = (1.f - z) * nn + z * h0[j];
            }
            *(f32x4*)&out[(size_t)node * 128 + d0] = o;
        }
    }
}

extern "C" void kernel_launch(void* const* d_in, const int* in_sizes, int n_in,
                              void* d_out, int out_size, void* d_ws, size_t ws_size,
                              hipStream_t stream)
{
    const float* h     = (const float*)d_in[0];
    const int*   ei    = (const int*)d_in[1];
    const int*   etype = (const int*)d_in[2];
    const float* W     = (const float*)d_in[3];
    const float* b     = (const float*)d_in[4];
    const float* wih   = (const float*)d_in[5];
    const float* whh   = (const float*)d_in[6];
    const float* bih   = (const float*)d_in[7];
    const float* bhh   = (const float*)d_in[8];
    float* out = (float*)d_out;

    int E = in_sizes[1] / 2;
    int N = in_sizes[0] / HID;
    int M8 = N * 8;
    int nbA = (M8 + 255) / 256;
    int capE = ((E + 127) / 128 + NTY) * 128;
    int nh = N * 128;

    char* p = (char*)d_ws;
    auto alloc = [&](size_t bytes) { char* r = p; p += (bytes + 255) & ~(size_t)255; return r; };
    unsigned short* hbf  = (unsigned short*)alloc((size_t)nh * 2);
    unsigned short* wfr  = (unsigned short*)alloc((size_t)131072 * 2);
    unsigned short* wpkf = (unsigned short*)alloc((size_t)98304 * 2);
    int* seg8    = (int*)alloc((size_t)M8 * 4);
    int* bsum    = (int*)alloc((size_t)nbA * 4);
    int* sortedE = (int*)alloc((size_t)capE * 4);
    int* padB    = (int*)alloc(9 * 4);
    int* padA    = (int*)alloc(8 * 4);
    int* trueE   = (int*)alloc(8 * 4);
    unsigned short* M = (unsigned short*)alloc((size_t)capE * 128 * 2);
    (void)ws_size;

    hipMemsetAsync(seg8, 0, (size_t)M8 * 4, stream);

    conv_hist<<<2048, 256, 0, stream>>>(h, hbf, nh, W, wfr, wih, whh, wpkf,
                                        ei, etype, E, N, seg8);
    scanA_kernel<<<nbA, 256, 0, stream>>>(seg8, bsum, M8);
    scanBbig_kernel<<<1, 256, 0, stream>>>(bsum, nbA, seg8, N, E, padB, padA, trueE);
    scatter8_kernel<<<1024, 256, 0, stream>>>(etype, ei, E, N, seg8, bsum, padA, sortedE);

    msg_gemm<<<capE / 128, 256, 0, stream>>>(hbf, wfr, b, sortedE, padB, trueE, M);
    gru_fused<<<(N + 63) / 64, 512, 0, stream>>>(M, seg8, bsum, padA, padB, hbf, wpkf,
                                                 bih, bhh, h, out, N);
}